// Round 4
// baseline (146.237 us; speedup 1.0000x reference)
//
#include <hip/hip_runtime.h>

#define N_NODES 32768
#define N_EDGES 65536

typedef _Float16 f16;
typedef _Float16 f16x8 __attribute__((ext_vector_type(8)));
typedef float f32x16 __attribute__((ext_vector_type(16)));
typedef unsigned int uint32;

// ---------------- ws layout ----------------
// [0, 8388608)            agg     float[N*64]
// [8388608, 8519680)      deg     float[N]
// [8519680, 9060352)      w2v2    f16, 66 j-rows x 8 octets x 1024 B (j 0..63 = W2, 64 = b2, 65 = 0)
// [9060352, 9068544)      w1v2    f16, 8 octets x 1024 B
// [9068544, 9076736)      rootIv2 f16 (root + I), 8 octets x 1024 B
#define WS_AGG   0
#define WS_DEG   8388608
#define WS_W2    8519680
#define WS_W1    9060352
#define WS_ROOT  9068544

#define MFMA(a, b, c) __builtin_amdgcn_mfma_f32_32x32x16_f16((a), (b), (c), 0, 0, 0)

__device__ inline f16 u16_as_f16(unsigned short u) {
  union { unsigned short s; f16 h; } v; v.s = u; return v.h;
}
__device__ inline f16x8 splat8(f16 x) {
  f16x8 r;
  #pragma unroll
  for (int u = 0; u < 8; ++u) r[u] = x;
  return r;
}
__device__ inline f16x8 cvt8(float4 p0, float4 p1) {
  f16x8 a;
  a[0] = (f16)p0.x; a[1] = (f16)p0.y; a[2] = (f16)p0.z; a[3] = (f16)p0.w;
  a[4] = (f16)p1.x; a[5] = (f16)p1.y; a[6] = (f16)p1.z; a[7] = (f16)p1.w;
  return a;
}

// ============ prep: coalesced float4 reads, small scattered f16 writes ============
// frag layout: oct = j*8 + (h>>4)*2 + ((h>>3)&1); byte = oct*1024 + col*16 + (h&7)*2
__global__ __launch_bounds__(256) void k_prep(const float* __restrict__ W1,
                                              const float* __restrict__ W2,
                                              const float* __restrict__ b2,
                                              const float* __restrict__ root,
                                              const int* __restrict__ eidx,
                                              float* __restrict__ deg,
                                              char* __restrict__ w2v2,
                                              char* __restrict__ w1v2,
                                              char* __restrict__ rootIv2) {
  int t = blockIdx.x * 256 + threadIdx.x;
  if (t < 65536) {                       // W2 rows j 0..63
    int j = t >> 10, rem = t & 1023, h = rem >> 4, c4 = rem & 15;
    float4 v = *(const float4*)(W2 + j * 4096 + h * 64 + c4 * 4);
    int oct = j * 8 + (h >> 4) * 2 + ((h >> 3) & 1);
    char* base = w2v2 + oct * 1024 + (h & 7) * 2;
    *(f16*)(base + (c4 * 4 + 0) * 16) = (f16)v.x;
    *(f16*)(base + (c4 * 4 + 1) * 16) = (f16)v.y;
    *(f16*)(base + (c4 * 4 + 2) * 16) = (f16)v.z;
    *(f16*)(base + (c4 * 4 + 3) * 16) = (f16)v.w;
  } else if (t < 66560) {                // b2 row j=64
    int u = t - 65536, h = u >> 4, c4 = u & 15;
    float4 v = *(const float4*)(b2 + h * 64 + c4 * 4);
    int oct = 512 + (h >> 4) * 2 + ((h >> 3) & 1);
    char* base = w2v2 + oct * 1024 + (h & 7) * 2;
    *(f16*)(base + (c4 * 4 + 0) * 16) = (f16)v.x;
    *(f16*)(base + (c4 * 4 + 1) * 16) = (f16)v.y;
    *(f16*)(base + (c4 * 4 + 2) * 16) = (f16)v.z;
    *(f16*)(base + (c4 * 4 + 3) * 16) = (f16)v.w;
  } else if (t < 67584) {                // zero row j=65
    int u = t - 66560, h = u >> 4, c4 = u & 15;
    int oct = 520 + (h >> 4) * 2 + ((h >> 3) & 1);
    char* base = w2v2 + oct * 1024 + (h & 7) * 2;
    #pragma unroll
    for (int q = 0; q < 4; ++q) *(f16*)(base + (c4 * 4 + q) * 16) = (f16)0.f;
  } else if (t < 68608) {                // W1
    int u = t - 67584, i = u >> 4, c4 = u & 15;
    float4 v = *(const float4*)(W1 + i * 64 + c4 * 4);
    int oct = (i >> 4) * 2 + ((i >> 3) & 1);
    char* base = w1v2 + oct * 1024 + (i & 7) * 2;
    *(f16*)(base + (c4 * 4 + 0) * 16) = (f16)v.x;
    *(f16*)(base + (c4 * 4 + 1) * 16) = (f16)v.y;
    *(f16*)(base + (c4 * 4 + 2) * 16) = (f16)v.z;
    *(f16*)(base + (c4 * 4 + 3) * 16) = (f16)v.w;
  } else if (t < 69632) {                // rootI = root + I
    int u = t - 68608, i = u >> 4, c4 = u & 15;
    float4 v = *(const float4*)(root + i * 64 + c4 * 4);
    int oct = (i >> 4) * 2 + ((i >> 3) & 1);
    char* base = rootIv2 + oct * 1024 + (i & 7) * 2;
    *(f16*)(base + (c4 * 4 + 0) * 16) = (f16)(v.x + (i == c4 * 4 + 0 ? 1.f : 0.f));
    *(f16*)(base + (c4 * 4 + 1) * 16) = (f16)(v.y + (i == c4 * 4 + 1 ? 1.f : 0.f));
    *(f16*)(base + (c4 * 4 + 2) * 16) = (f16)(v.z + (i == c4 * 4 + 2 ? 1.f : 0.f));
    *(f16*)(base + (c4 * 4 + 3) * 16) = (f16)(v.w + (i == c4 * 4 + 3 ? 1.f : 0.f));
  } else if (t < 135168) {               // degree histogram
    int e = t - 69632;
    unsafeAtomicAdd(&deg[eidx[N_EDGES + e]], 1.0f);
  }
}

__device__ inline void chunk_load(f16x8 (&buf)[8], const char* wp, int c) {
  #pragma unroll
  for (int jj = 0; jj < 2; ++jj)
    #pragma unroll
    for (int kk = 0; kk < 4; ++kk)
      buf[jj * 4 + kk] = *(const f16x8*)(wp + c * 16384 + ((jj * 8 + kk * 2) << 10));
}

__device__ inline void chunk_compute(const f16x8 (&buf)[8], uint32 hA, uint32 hB,
                                     const f16x8 (&xf)[2][4], f32x16 (&acc)[2]) {
  #pragma unroll
  for (int jj = 0; jj < 2; ++jj) {
    const f16x8 spA = splat8(u16_as_f16((unsigned short)(hA >> (jj * 16))));
    const f16x8 spB = splat8(u16_as_f16((unsigned short)(hB >> (jj * 16))));
    #pragma unroll
    for (int kk = 0; kk < 4; ++kk) {
      acc[0] = MFMA(xf[0][kk] * spA, buf[jj * 4 + kk], acc[0]);
      acc[1] = MFMA(xf[1][kk] * spB, buf[jj * 4 + kk], acc[1]);
    }
  }
}

// ============ main: 256 blocks x 512 thr (8 waves, 2/SIMD); B direct from L2; depth-2 reg pipeline ============
__global__ __launch_bounds__(512, 2) void k_main(const float* __restrict__ node,
                                                 const float* __restrict__ edge,
                                                 const float* __restrict__ b1,
                                                 const int* __restrict__ eidx,
                                                 const char* __restrict__ w2v2,
                                                 const char* __restrict__ w1v2,
                                                 float* __restrict__ agg) {
  __shared__ char ldsH[34816];           // 256 edges x 136 B (66 j-f16 + pad)

  const int tid = threadIdx.x;
  const int lane = tid & 63;
  const int wv = tid >> 6;               // 0..7
  const int ln31 = lane & 31;
  const int half = lane >> 5;
  const int ebase = blockIdx.x * 256;

  // ---- phase 1: wave wv computes h = relu(ee@W1+b1) for tile wv ----
  {
    const char* w1p = w1v2 + half * 1024 + ln31 * 16;
    const int e = ebase + wv * 32 + ln31;
    const float4* er = (const float4*)edge + (long)e * 16;
    f32x16 c0 = {}, c1 = {};
    #pragma unroll
    for (int kk = 0; kk < 4; ++kk) {
      f16x8 a = cvt8(er[kk * 4 + half * 2], er[kk * 4 + half * 2 + 1]);
      f16x8 bf0 = *(const f16x8*)(w1p + (kk * 2 << 10));
      f16x8 bf1 = *(const f16x8*)(w1p + (kk * 2 << 10) + 512);
      c0 = MFMA(a, bf0, c0);
      c1 = MFMA(a, bf1, c1);
    }
    const float bb0 = b1[ln31], bb1 = b1[32 + ln31];
    char* hb = ldsH + wv * 32 * 136;
    #pragma unroll
    for (int r = 0; r < 16; ++r) {
      const int m = (r & 3) + 8 * (r >> 2) + 4 * half;
      *(f16*)(hb + m * 136 + ln31 * 2)      = (f16)fmaxf(c0[r] + bb0, 0.f);
      *(f16*)(hb + m * 136 + 64 + ln31 * 2) = (f16)fmaxf(c1[r] + bb1, 0.f);
    }
    if (half == 0)                        // j=64 bias row -> h=1.0, j=65 -> 0
      *(uint32*)(hb + ln31 * 136 + 128) = 0x00003C00u;
  }

  const int g = wv >> 1;                 // edge group: tiles 2g, 2g+1
  const int ch = wv & 1;                 // output col half

  // ---- gather x = node_emb[src] fragments ----
  f16x8 xf[2][4];
  #pragma unroll
  for (int t = 0; t < 2; ++t) {
    const int e = ebase + (2 * g + t) * 32 + ln31;
    const int s = eidx[e];
    const float4* xr = (const float4*)node + (long)s * 16;
    #pragma unroll
    for (int kk = 0; kk < 4; ++kk)
      xf[t][kk] = cvt8(xr[kk * 4 + half * 2], xr[kk * 4 + half * 2 + 1]);
  }

  const char* wp = w2v2 + half * 1024 + ch * 512 + ln31 * 16;
  const char* hpA = ldsH + ((2 * g + 0) * 32 + ln31) * 136;
  const char* hpB = ldsH + ((2 * g + 1) * 32 + ln31) * 136;

  f16x8 b0[8], b1v[8];
  f32x16 acc[2] = {};
  chunk_load(b0, wp, 0);

  __syncthreads();                       // ldsH ready

  // ---- K loop: 33 chunks of 2 j-rows (j 0..65 incl bias+zero), depth-2 pipeline ----
  for (int c = 0; c < 32; c += 2) {
    chunk_load(b1v, wp, c + 1);
    const uint32 hA0 = *(const uint32*)(hpA + c * 4);
    const uint32 hB0 = *(const uint32*)(hpB + c * 4);
    const uint32 hA1 = *(const uint32*)(hpA + c * 4 + 4);
    const uint32 hB1 = *(const uint32*)(hpB + c * 4 + 4);
    __builtin_amdgcn_s_setprio(1);
    chunk_compute(b0, hA0, hB0, xf, acc);
    __builtin_amdgcn_s_setprio(0);
    chunk_load(b0, wp, c + 2);
    __builtin_amdgcn_s_setprio(1);
    chunk_compute(b1v, hA1, hB1, xf, acc);
    __builtin_amdgcn_s_setprio(0);
  }
  {                                      // tail: chunk 32 (j 64 = bias, j 65 = zero)
    const uint32 hA = *(const uint32*)(hpA + 128);
    const uint32 hB = *(const uint32*)(hpB + 128);
    chunk_compute(b0, hA, hB, xf, acc);
  }

  // ---- scatter-add msg into agg[dst] ----
  #pragma unroll
  for (int t = 0; t < 2; ++t) {
    const int base_e = ebase + (2 * g + t) * 32;
    #pragma unroll
    for (int r = 0; r < 16; ++r) {
      const int m = (r & 3) + 8 * (r >> 2) + 4 * half;
      const int d = eidx[N_EDGES + base_e + m];
      unsafeAtomicAdd(&agg[(long)d * 64 + ch * 32 + ln31], acc[t][r]);
    }
  }
}

// ============ node epilogue: MFMA (root+I) transform + mean-agg + LayerNorm ============
__global__ __launch_bounds__(256) void k_node(const float* __restrict__ node,
                                              const float* __restrict__ agg,
                                              const float* __restrict__ deg,
                                              const char* __restrict__ rootIv2,
                                              const float* __restrict__ bias,
                                              const float* __restrict__ gamma,
                                              const float* __restrict__ beta,
                                              float* __restrict__ out) {
  const int tid = threadIdx.x;
  const int lane = tid & 63;
  const int wv = tid >> 6;
  const int ln31 = lane & 31;
  const int half = lane >> 5;
  const int nb = blockIdx.x * 128 + wv * 32;

  const char* rp = rootIv2 + half * 1024 + ln31 * 16;
  f32x16 c0 = {}, c1 = {};
  const float4* xr = (const float4*)node + (long)(nb + ln31) * 16;
  #pragma unroll
  for (int kk = 0; kk < 4; ++kk) {
    f16x8 a = cvt8(xr[kk * 4 + half * 2], xr[kk * 4 + half * 2 + 1]);
    f16x8 b0 = *(const f16x8*)(rp + (kk * 2 << 10));
    f16x8 b1f = *(const f16x8*)(rp + (kk * 2 << 10) + 512);
    c0 = MFMA(a, b0, c0);
    c1 = MFMA(a, b1f, c1);
  }
  const float bi0 = bias[ln31],  bi1 = bias[32 + ln31];
  const float g0  = gamma[ln31], g1  = gamma[32 + ln31];
  const float be0 = beta[ln31],  be1 = beta[32 + ln31];
  #pragma unroll
  for (int r = 0; r < 16; ++r) {
    const int m = (r & 3) + 8 * (r >> 2) + 4 * half;
    const int n = nb + m;
    const float rd = 1.f / fmaxf(deg[n], 1.f);
    const float pre0 = agg[n * 64 + ln31] * rd + c0[r] + bi0;
    const float pre1 = agg[n * 64 + 32 + ln31] * rd + c1[r] + bi1;
    float s = pre0 + pre1, s2 = pre0 * pre0 + pre1 * pre1;
    #pragma unroll
    for (int mk = 16; mk >= 1; mk >>= 1) {
      s  += __shfl_xor(s, mk, 64);
      s2 += __shfl_xor(s2, mk, 64);
    }
    const float mu  = s * 0.015625f;
    const float var = s2 * 0.015625f - mu * mu;
    const float inv = rsqrtf(var + 1e-5f);
    out[n * 64 + ln31]      = (pre0 - mu) * inv * g0 + be0;
    out[n * 64 + 32 + ln31] = (pre1 - mu) * inv * g1 + be1;
  }
}

extern "C" void kernel_launch(void* const* d_in, const int* in_sizes, int n_in,
                              void* d_out, int out_size, void* d_ws, size_t ws_size,
                              hipStream_t stream) {
  const float* node  = (const float*)d_in[0];
  const float* edgee = (const float*)d_in[1];
  const float* W1    = (const float*)d_in[2];
  const float* b1    = (const float*)d_in[3];
  const float* W2    = (const float*)d_in[4];
  const float* b2    = (const float*)d_in[5];
  const float* root  = (const float*)d_in[6];
  const float* bias  = (const float*)d_in[7];
  const float* gamma = (const float*)d_in[8];
  const float* beta  = (const float*)d_in[9];
  const int*   eidx  = (const int*)d_in[10];
  float* out = (float*)d_out;

  char* ws = (char*)d_ws;
  float* agg     = (float*)(ws + WS_AGG);
  float* deg     = (float*)(ws + WS_DEG);
  char*  w2v2    = ws + WS_W2;
  char*  w1v2    = ws + WS_W1;
  char*  rootIv2 = ws + WS_ROOT;

  hipMemsetAsync(ws, 0, 8519680, stream);   // zero agg + deg

  k_prep<<<528, 256, 0, stream>>>(W1, W2, b2, root, eidx, deg, w2v2, w1v2, rootIv2);
  k_main<<<256, 512, 0, stream>>>(node, edgee, b1, eidx, w2v2, w1v2, agg);
  k_node<<<256, 256, 0, stream>>>(node, agg, deg, rootIv2, bias, gamma, beta, out);
}